// Round 9
// baseline (826.143 us; speedup 1.0000x reference)
//
#include <hip/hip_runtime.h>

// LightGCN encoder, round 9.
// Round-8 post-mortem: SpMM is now ~half VALU-bound (VALUBusy 65%, 115us of
// 177us): 16 ds_bpermute (__shfl) + 64-bit vector gather addressing per
// 8-edge iter. Fix: broadcast lane index is wave-uniform -> readlane (VALU,
// ->SGPR, no DS); gather pointer built scalar-side so the load is
// global_load(saddr + lane*4) with ~zero per-gather VALU. CSR build pipeline
// (round-7, atomic-free) and FIRST/LAST fusion unchanged.

#define USER_NUM 100000
#define ITEM_NUM 50000
#define N_NODES (USER_NUM + ITEM_NUM)
#define EMB 64
#define NFLOAT (N_NODES * EMB)

#define SHIFT2 9
#define RPB 512                               // rows per bucket
#define NB2 ((N_NODES + RPB - 1) / RPB)       // 293 buckets
#define COLMASK 0x3FFFF                       // col < 150000 < 2^18

// ---------------- bucket histogram (LDS-privatized, no per-edge global atomics)
__global__ __launch_bounds__(256) void k_hist(const int* __restrict__ row,
                                              int* __restrict__ ghist, int nnz) {
    __shared__ int cnt[NB2];
    for (int t = threadIdx.x; t < NB2; t += 256) cnt[t] = 0;
    __syncthreads();
    int stride = gridDim.x * blockDim.x;
    for (int i = blockIdx.x * blockDim.x + threadIdx.x; i < nnz; i += stride)
        atomicAdd(&cnt[row[i] >> SHIFT2], 1);
    __syncthreads();
    for (int t = threadIdx.x; t < NB2; t += 256) {
        int c = cnt[t];
        if (c) atomicAdd(&ghist[t], c);
    }
}

// ---------------- bucket exclusive scan (LDS-staged, serial core over 293)
__global__ __launch_bounds__(512) void k_top(const int* __restrict__ ghist,
                                             int* __restrict__ bstart,
                                             int* __restrict__ bcursor, int nnz) {
    __shared__ int buf[NB2];
    for (int t = threadIdx.x; t < NB2; t += 512) buf[t] = ghist[t];
    __syncthreads();
    if (threadIdx.x == 0) {
        int run = 0;
        for (int b = 0; b < NB2; ++b) { int c = buf[b]; buf[b] = run; run += c; }
    }
    __syncthreads();
    for (int t = threadIdx.x; t < NB2; t += 512) {
        bstart[t] = buf[t];
        bcursor[t] = buf[t];
    }
    if (threadIdx.x == 0) bstart[NB2] = nnz;
}

// ---------------- phase 1: scatter edges into bucket-contiguous packed array
#define SC_EPT 32
#define SC_CHUNK (256 * SC_EPT)
__global__ __launch_bounds__(256) void k_scat1(const int* __restrict__ row,
                                               const int* __restrict__ col,
                                               const float* __restrict__ vals,
                                               int* __restrict__ bcursor,
                                               uint2* __restrict__ packed, int nnz) {
    __shared__ int cnt[NB2];
    __shared__ int base[NB2];
    for (int t = threadIdx.x; t < NB2; t += 256) cnt[t] = 0;
    __syncthreads();
    long long start = (long long)blockIdx.x * SC_CHUNK;
    for (int k = 0; k < SC_EPT; ++k) {
        long long i = start + k * 256 + threadIdx.x;
        if (i < nnz) atomicAdd(&cnt[row[i] >> SHIFT2], 1);
    }
    __syncthreads();
    for (int t = threadIdx.x; t < NB2; t += 256) {
        int c = cnt[t];
        base[t] = c ? atomicAdd(&bcursor[t], c) : 0;
        cnt[t] = 0;
    }
    __syncthreads();
    for (int k = 0; k < SC_EPT; ++k) {
        long long i = start + k * 256 + threadIdx.x;
        if (i < nnz) {
            int r = row[i];
            int b = r >> SHIFT2;
            int l = atomicAdd(&cnt[b], 1);
            packed[base[b] + l] =
                make_uint2(((unsigned)(r & (RPB - 1)) << 18) | (unsigned)col[i],
                           __float_as_uint(vals[i]));
        }
    }
}

// ---------------- phase 2: per-bucket counting sort -> final CSR + rowptr
__global__ __launch_bounds__(1024) void k_sort(const uint2* __restrict__ packed,
                                               const int* __restrict__ bstart,
                                               uint2* __restrict__ bkv,
                                               int* __restrict__ rowptr, int nnz) {
    __shared__ int cnt[RPB];
    __shared__ int scn[RPB];
    const int b = blockIdx.x;
    const int s = bstart[b], e = bstart[b + 1];
    if (threadIdx.x < RPB) cnt[threadIdx.x] = 0;
    __syncthreads();
    for (int i = s + threadIdx.x; i < e; i += 1024)
        atomicAdd(&cnt[packed[i].x >> 18], 1);
    __syncthreads();
    if (threadIdx.x < RPB) scn[threadIdx.x] = cnt[threadIdx.x];
    __syncthreads();
    for (int off = 1; off < RPB; off <<= 1) {
        int v = 0;
        if (threadIdx.x < RPB && threadIdx.x >= off) v = scn[threadIdx.x - off];
        __syncthreads();
        if (threadIdx.x < RPB) scn[threadIdx.x] += v;
        __syncthreads();
    }
    const int grow0 = b << SHIFT2;
    if (threadIdx.x < RPB) {
        int start = s + scn[threadIdx.x] - cnt[threadIdx.x];
        int gr = grow0 + threadIdx.x;
        if (gr < N_NODES) rowptr[gr] = start;
        cnt[threadIdx.x] = start;
    }
    if (b == 0 && threadIdx.x == 0) rowptr[N_NODES] = nnz;
    __syncthreads();
    for (int i = s + threadIdx.x; i < e; i += 1024) {
        uint2 kv = packed[i];
        int lr = kv.x >> 18;
        int pos = atomicAdd(&cnt[lr], 1);
        bkv[pos] = make_uint2(kv.x & COLMASK, kv.y);
    }
}

// ---------------- pull SpMM: one wave per output row ----------------
// Staged coalesced edge load -> readlane broadcast (no DS ops) -> scalar-base
// gather global_load(saddr, lane*4). acc in one VGPR per lane.
template <bool FIRST, bool LAST>
__global__ __launch_bounds__(256) void lgcn_spmm_pull(const uint2* __restrict__ bkv,
                                                      const int* __restrict__ rowptr,
                                                      const float* __restrict__ xu,
                                                      const float* __restrict__ xi,
                                                      float* __restrict__ h_next,
                                                      float* __restrict__ acc) {
    const int lane = threadIdx.x & 63;
    const int wid = threadIdx.x >> 6;
    const int r = blockIdx.x * 4 + wid;
    if (r >= N_NODES) return;

    const int s = rowptr[r];
    const int deg = rowptr[r + 1] - s;
    const uint2* ebase = bkv + s;

    float a = 0.f;
    for (int base = 0; base < deg; base += 64) {
        int n = deg - base;
        if (n > 64) n = 64;
        uint2 kv = make_uint2(0u, 0u);
        if (lane < n) kv = ebase[base + lane];
        int k = 0;
        for (; k + 8 <= n; k += 8) {
            float xs[8], vv[8];
            #pragma unroll
            for (int J = 0; J < 8; ++J) {
                int cJ = __builtin_amdgcn_readlane((int)kv.x, k + J);   // SGPR
                vv[J] = __uint_as_float(__builtin_amdgcn_readlane((int)kv.y, k + J));
                const float* pJ = FIRST
                    ? ((cJ < USER_NUM) ? (xu + ((size_t)cJ << 6))
                                       : (xi + (((size_t)(cJ - USER_NUM)) << 6)))
                    : (xu + ((size_t)cJ << 6));                         // SALU
                xs[J] = pJ[lane];                                       // saddr+lane*4
            }
            #pragma unroll
            for (int J = 0; J < 8; ++J) a = fmaf(vv[J], xs[J], a);
        }
        for (; k < n; ++k) {
            int c = __builtin_amdgcn_readlane((int)kv.x, k);
            float v = __uint_as_float(__builtin_amdgcn_readlane((int)kv.y, k));
            const float* p = FIRST
                ? ((c < USER_NUM) ? (xu + ((size_t)c << 6))
                                  : (xi + (((size_t)(c - USER_NUM)) << 6)))
                : (xu + ((size_t)c << 6));
            a = fmaf(v, p[lane], a);
        }
    }

    const int o = (r << 6) + lane;
    if (!LAST) h_next[o] = a;
    if (FIRST) {
        float ego = (r < USER_NUM) ? xu[o] : xi[(((size_t)(r - USER_NUM)) << 6) + lane];
        acc[o] = 0.25f * (ego + a);
    } else {
        acc[o] += 0.25f * a;
    }
}

extern "C" void kernel_launch(void* const* d_in, const int* in_sizes, int n_in,
                              void* d_out, int out_size, void* d_ws, size_t ws_size,
                              hipStream_t stream) {
    const float* user_emb = (const float*)d_in[0];
    const float* item_emb = (const float*)d_in[1];
    const int* adj_row = (const int*)d_in[2];
    const int* adj_col = (const int*)d_in[3];
    const float* adj_vals = (const float*)d_in[4];
    const int nnz = in_sizes[2];

    float* acc = (float*)d_out;

    char* ws = (char*)d_ws;
    float* h1 = (float*)ws;                       ws += (size_t)NFLOAT * 4;
    char* region2 = ws;                           ws += (size_t)NFLOAT * 4;
    uint2* packed = (uint2*)region2;              // dead after k_sort
    float* h2 = (float*)region2;                  // reuses packed's space
    uint2* bkv = (uint2*)ws;                      ws += (size_t)nnz * 8;
    int* rowptr = (int*)ws;                       ws += (size_t)(N_NODES + 1) * 4;
    int* ghist = (int*)ws;                        ws += (size_t)NB2 * 4;
    int* bstart = (int*)ws;                       ws += (size_t)(NB2 + 1) * 4;
    int* bcursor = (int*)ws;                      ws += (size_t)NB2 * 4;

    // --- CSR build: hist -> bucket scan -> bucket scatter -> per-bucket sort
    hipMemsetAsync(ghist, 0, (size_t)NB2 * 4, stream);
    k_hist<<<512, 256, 0, stream>>>(adj_row, ghist, nnz);
    k_top<<<1, 512, 0, stream>>>(ghist, bstart, bcursor, nnz);
    int sc_blocks = (nnz + SC_CHUNK - 1) / SC_CHUNK;
    k_scat1<<<sc_blocks, 256, 0, stream>>>(adj_row, adj_col, adj_vals,
                                           bcursor, packed, nnz);
    k_sort<<<NB2, 1024, 0, stream>>>(packed, bstart, bkv, rowptr, nnz);

    // --- 3 propagation layers (pull); layer 1 reads ego directly, seeds acc
    const int grid = (N_NODES + 3) / 4;
    lgcn_spmm_pull<true,  false><<<grid, 256, 0, stream>>>(bkv, rowptr, user_emb, item_emb, h1, acc);
    lgcn_spmm_pull<false, false><<<grid, 256, 0, stream>>>(bkv, rowptr, h1, nullptr, h2, acc);
    lgcn_spmm_pull<false, true ><<<grid, 256, 0, stream>>>(bkv, rowptr, h2, nullptr, nullptr, acc);
}